// Round 1
// baseline (148.861 us; speedup 1.0000x reference)
//
#include <hip/hip_runtime.h>

#define TT 30
#define TD 150
#define NEGV -1e30f

// One block per batch row. 128 threads, each owns 4 consecutive dims (float4).
// Embedding row = 512 floats = 128 lanes * 16B = one fully-coalesced load.
__global__ __launch_bounds__(128) void swem_pool_kernel(
    const int* __restrict__ title, const int* __restrict__ desc,
    const int* __restrict__ t_len, const int* __restrict__ d_len,
    const float4* __restrict__ w2v, float4* __restrict__ out)
{
    __shared__ int s_idx[TT + TD];
    const int b = blockIdx.x;
    const int tid = threadIdx.x;

    // Preload this row's token indices into LDS (broadcast reads later).
    if (tid < TT) s_idx[tid] = title[b * TT + tid];
    for (int i = tid; i < TD; i += 128) s_idx[TT + i] = desc[b * TD + i];
    __syncthreads();

    const int tl = t_len[b];
    const int dl = d_len[b];

    // ---- title pool ----
    float4 mx = make_float4(NEGV, NEGV, NEGV, NEGV);
    float4 sm = make_float4(0.f, 0.f, 0.f, 0.f);
    for (int t = 0; t < tl; ++t) {
        const float4 v = w2v[(size_t)s_idx[t] * 128 + tid];
        mx.x = fmaxf(mx.x, v.x); mx.y = fmaxf(mx.y, v.y);
        mx.z = fmaxf(mx.z, v.z); mx.w = fmaxf(mx.w, v.w);
        sm.x += v.x; sm.y += v.y; sm.z += v.z; sm.w += v.w;
    }
    float4 tmax, tavg;
    if (tl > 0) {
        const float inv = 1.0f / (float)tl;
        tmax = mx;
        tavg = make_float4(sm.x * inv, sm.y * inv, sm.z * inv, sm.w * inv);
    } else {
        tmax = make_float4(0.f, 0.f, 0.f, 0.f);
        tavg = make_float4(0.f, 0.f, 0.f, 0.f);
    }

    // ---- desc pool ----
    mx = make_float4(NEGV, NEGV, NEGV, NEGV);
    sm = make_float4(0.f, 0.f, 0.f, 0.f);
    for (int t = 0; t < dl; ++t) {
        const float4 v = w2v[(size_t)s_idx[TT + t] * 128 + tid];
        mx.x = fmaxf(mx.x, v.x); mx.y = fmaxf(mx.y, v.y);
        mx.z = fmaxf(mx.z, v.z); mx.w = fmaxf(mx.w, v.w);
        sm.x += v.x; sm.y += v.y; sm.z += v.z; sm.w += v.w;
    }
    float4 dmax, davg;
    if (dl > 0) {
        const float inv = 1.0f / (float)dl;
        dmax = mx;
        davg = make_float4(sm.x * inv, sm.y * inv, sm.z * inv, sm.w * inv);
    } else {
        dmax = make_float4(0.f, 0.f, 0.f, 0.f);
        davg = make_float4(0.f, 0.f, 0.f, 0.f);
    }

    // ---- write: out row = [t_max(512) | d_max(512) | t_avg(512) | d_avg(512)]
    // = 512 float4s per row; this thread writes slots tid, 128+tid, 256+tid, 384+tid.
    float4* orow = out + (size_t)b * 512;
    orow[tid]       = tmax;
    orow[128 + tid] = dmax;
    orow[256 + tid] = tavg;
    orow[384 + tid] = davg;
}

extern "C" void kernel_launch(void* const* d_in, const int* in_sizes, int n_in,
                              void* d_out, int out_size, void* d_ws, size_t ws_size,
                              hipStream_t stream) {
    const int* title = (const int*)d_in[0];   // (2048, 30)
    const int* desc  = (const int*)d_in[1];   // (2048, 150)
    const int* t_len = (const int*)d_in[2];   // (2048,)
    const int* d_len = (const int*)d_in[3];   // (2048,)
    // d_in[4] = mode (unused)
    const float4* w2v = (const float4*)d_in[5]; // (34836, 512) fp32, 128 float4/row

    float4* out = (float4*)d_out;             // (2048, 2048) fp32

    const int B = in_sizes[2];                // 2048
    swem_pool_kernel<<<B, 128, 0, stream>>>(title, desc, t_len, d_len, w2v, out);
}

// Round 2
// 148.582 us; speedup vs baseline: 1.0019x; 1.0019x over previous
//
#include <hip/hip_runtime.h>

#define TT 30
#define TD 150
#define NEGV -1e30f
#define NGRP 4          // token groups per block
#define LANES 128       // dim lanes (512 floats / 4 per float4)

// Grid: (B, 2). blockIdx.y == 0 -> title segment, 1 -> desc segment.
// Block: 512 threads = NGRP groups x 128 lanes. Group g handles tokens
// g, g+4, g+8, ...; each lane owns 4 consecutive dims (one float4 of the
// 2KB embedding row -> fully coalesced 2KB transaction per group-load).
// Partial max/sum reduced across groups through LDS (conflict-free layout).
__global__ __launch_bounds__(512) void swem_pool_kernel(
    const int* __restrict__ title, const int* __restrict__ desc,
    const int* __restrict__ t_len, const int* __restrict__ d_len,
    const float4* __restrict__ w2v, float4* __restrict__ out)
{
    __shared__ int s_idx[TD];
    // [quantity 0..7 = max.xyzw, sum.xyzw][group][lane] -- 4B stride across
    // lanes => conflict-free ds_read/ds_write.
    __shared__ float red[8][NGRP][LANES];

    const int b    = blockIdx.x;
    const int seg  = blockIdx.y;            // 0=title, 1=desc
    const int tid  = threadIdx.x;
    const int lane = tid & (LANES - 1);
    const int grp  = tid >> 7;

    const int* toks   = seg ? (desc + b * TD) : (title + b * TT);
    const int  maxlen = seg ? TD : TT;
    const int  len    = seg ? d_len[b] : t_len[b];

    for (int i = tid; i < maxlen; i += 512) s_idx[i] = toks[i];
    __syncthreads();

    float4 mx = make_float4(NEGV, NEGV, NEGV, NEGV);
    float4 sm = make_float4(0.f, 0.f, 0.f, 0.f);
    #pragma unroll 4
    for (int t = grp; t < len; t += NGRP) {
        const float4 v = w2v[(size_t)s_idx[t] * 128 + lane];
        mx.x = fmaxf(mx.x, v.x); mx.y = fmaxf(mx.y, v.y);
        mx.z = fmaxf(mx.z, v.z); mx.w = fmaxf(mx.w, v.w);
        sm.x += v.x; sm.y += v.y; sm.z += v.z; sm.w += v.w;
    }

    red[0][grp][lane] = mx.x; red[1][grp][lane] = mx.y;
    red[2][grp][lane] = mx.z; red[3][grp][lane] = mx.w;
    red[4][grp][lane] = sm.x; red[5][grp][lane] = sm.y;
    red[6][grp][lane] = sm.z; red[7][grp][lane] = sm.w;
    __syncthreads();

    // out row layout (float4 slots): [t_max:0 | d_max:128 | t_avg:256 | d_avg:384]
    float4* orow = out + (size_t)b * 512;

    if (grp == 0) {           // final max
        float4 r;
        r.x = fmaxf(fmaxf(red[0][0][lane], red[0][1][lane]),
                    fmaxf(red[0][2][lane], red[0][3][lane]));
        r.y = fmaxf(fmaxf(red[1][0][lane], red[1][1][lane]),
                    fmaxf(red[1][2][lane], red[1][3][lane]));
        r.z = fmaxf(fmaxf(red[2][0][lane], red[2][1][lane]),
                    fmaxf(red[2][2][lane], red[2][3][lane]));
        r.w = fmaxf(fmaxf(red[3][0][lane], red[3][1][lane]),
                    fmaxf(red[3][2][lane], red[3][3][lane]));
        if (len == 0) r = make_float4(0.f, 0.f, 0.f, 0.f);
        orow[seg * 128 + lane] = r;
    } else if (grp == 1) {    // final mean
        const float inv = 1.0f / (float)(len > 0 ? len : 1);
        float4 r;
        r.x = (red[4][0][lane] + red[4][1][lane] + red[4][2][lane] + red[4][3][lane]) * inv;
        r.y = (red[5][0][lane] + red[5][1][lane] + red[5][2][lane] + red[5][3][lane]) * inv;
        r.z = (red[6][0][lane] + red[6][1][lane] + red[6][2][lane] + red[6][3][lane]) * inv;
        r.w = (red[7][0][lane] + red[7][1][lane] + red[7][2][lane] + red[7][3][lane]) * inv;
        if (len == 0) r = make_float4(0.f, 0.f, 0.f, 0.f);
        orow[256 + seg * 128 + lane] = r;
    }
}

extern "C" void kernel_launch(void* const* d_in, const int* in_sizes, int n_in,
                              void* d_out, int out_size, void* d_ws, size_t ws_size,
                              hipStream_t stream) {
    const int* title = (const int*)d_in[0];     // (2048, 30)
    const int* desc  = (const int*)d_in[1];     // (2048, 150)
    const int* t_len = (const int*)d_in[2];     // (2048,)
    const int* d_len = (const int*)d_in[3];     // (2048,)
    // d_in[4] = mode (unused)
    const float4* w2v = (const float4*)d_in[5]; // (34836, 512) fp32

    float4* out = (float4*)d_out;               // (2048, 2048) fp32
    const int B = in_sizes[2];                  // 2048

    dim3 grid(B, 2);
    swem_pool_kernel<<<grid, 512, 0, stream>>>(title, desc, t_len, d_len, w2v, out);
}